// Round 5
// baseline (710.839 us; speedup 1.0000x reference)
//
#include <hip/hip_runtime.h>

#define H 256
#define XROW 1040            // LDS bytes per x row (1024 + 16 pad)
#define WPAIR 1040           // LDS bytes per W row-pair (1024 + 16 pad)
#define HROW 528             // LDS bytes per h row (512 + 16 pad)
#define XL_OFF 0
#define WB0_OFF 66560
#define WB1_OFF 99840
#define SMEM_BYTES 133120    // 130 KB -> 1 block/CU

typedef short bf16x8 __attribute__((ext_vector_type(8)));
typedef float f32x4  __attribute__((ext_vector_type(4)));

__device__ __forceinline__ unsigned int f2bf(float f) {
    unsigned int u = __float_as_uint(f);
    return (u + 0x7fffu + ((u >> 16) & 1u)) >> 16;   // RNE to bf16
}
__device__ __forceinline__ int clamp_seg(int s) { return s < 0 ? 0 : (s > 511 ? 511 : s); }

// fire-and-forget global->LDS DMA: 64 lanes x 16B -> contiguous 1024B at
// wave-uniform lds base + lane*16. Cannot be sunk by the scheduler.
__device__ __forceinline__ void glds16(const void* gp, void* lp) {
    __builtin_amdgcn_global_load_lds(
        (const __attribute__((address_space(1))) void*)gp,
        (__attribute__((address_space(3))) void*)lp, 16, 0, 0);
}

__global__ void conv_w_kernel(const float* __restrict__ W1, const float* __restrict__ W2,
                              unsigned short* __restrict__ W1b, unsigned short* __restrict__ W2b) {
    int i = blockIdx.x * 256 + threadIdx.x;           // 256 blocks x 256 = 65536
    W1b[i] = (unsigned short)f2bf(W1[i]);
    W2b[i] = (unsigned short)f2bf(W2[i]);
}

// Fused: h = relu(x@W1^T+b1); g = h*sigmoid(h@W2^T+b2); segment max/sum.
// 64-row tile/block; wave(rh=w&1, ch=w>>1) owns rows 32rh..+32, cols 128ch..+128.
// MFMA 16x16x32 bf16: A[m=lane&15][k=q*8+j]; B[k=q*8+j][n=lane&15];
// C/D: col=lane&15, row=q*4+e.  (verified R1-R4)
// All global->LDS movement via glds16; W chunks double-buffered, 8-chunk pipeline.
__global__ __launch_bounds__(256, 1) void fused_main(
    const float* __restrict__ x, const int* __restrict__ batch,
    const unsigned short* __restrict__ W1b, const float* __restrict__ b1,
    const unsigned short* __restrict__ W2b, const float* __restrict__ b2,
    float* __restrict__ out, int* __restrict__ counts)
{
    __shared__ __align__(16) unsigned char smem[SMEM_BYTES];

    const int tid  = threadIdx.x;
    const int wave = tid >> 6;
    const int lane = tid & 63;
    const int r    = lane & 15;
    const int q    = lane >> 4;
    const int rh   = wave & 1;    // row half  (32 rows)
    const int ch   = wave >> 1;   // col half  (128 cols)
    const int r0   = blockIdx.x * 64;

    // ---- stage x tile: wave stages rows 16w..16w+16 (1 instr = 1 row = 1024B)
    {
        const unsigned char* xb = (const unsigned char*)(x + (size_t)r0 * H);
#pragma unroll
        for (int i = 0; i < 16; ++i) {
            const int row = wave * 16 + i;
            glds16(xb + (size_t)row * 1024 + (size_t)lane * 16, smem + XL_OFF + row * XROW);
        }
    }

    // ---- W chunk stager: chunk c = W rows {32c..+32} U {128+32c..+32}
    //      (so every wave gets its 32-col slice from every chunk)
    auto stageW = [&](const unsigned short* Wg, int c, int boff) {
#pragma unroll
        for (int i = 0; i < 8; ++i) {
            const int p  = wave * 8 + i;                      // pair index 0..31 (wave-uniform)
            const int wr = (p < 16) ? (32 * c + 2 * p) : (128 + 32 * c + 2 * (p - 16));
            glds16((const unsigned char*)Wg + (size_t)wr * 512 + (size_t)lane * 16,
                   smem + boff + p * WPAIR);
        }
    };
    stageW(W1b, 0, WB0_OFF);

    // ---- segment bookkeeping + bias preload (latency overlapped with staging)
    const int  wseg0 = batch[r0 + 32 * rh];
    const bool wuni  = (wseg0 == batch[r0 + 32 * rh + 31]);
    const int  wsegc = clamp_seg(wseg0);
    int msegc[2]; bool muni[2]; int esegc[2][4];
#pragma unroll
    for (int ms = 0; ms < 2; ++ms) {
        const int rb = r0 + 32 * rh + 16 * ms;
        const int s0 = batch[rb];
        muni[ms]  = (s0 == batch[rb + 15]);
        msegc[ms] = clamp_seg(s0);
#pragma unroll
        for (int e = 0; e < 4; ++e) esegc[ms][e] = clamp_seg(batch[rb + q * 4 + e]);
    }
    float bias1[4][2], bias2[4][2];
#pragma unroll
    for (int c = 0; c < 4; ++c)
#pragma unroll
        for (int ns = 0; ns < 2; ++ns) {
            const int col = 128 * ch + 32 * c + 16 * ns + r;
            bias1[c][ns] = b1[col];
            bias2[c][ns] = b2[col];
        }

    __syncthreads();   // x tile + W1 chunk0 resident

    // ---- A1 fragments from xl (fp32 -> bf16), 2 b128 per frag
    bf16x8 a1[2][8];
#pragma unroll
    for (int ms = 0; ms < 2; ++ms)
#pragma unroll
        for (int kc = 0; kc < 8; ++kc) {
            const unsigned char* p = smem + XL_OFF + (32 * rh + 16 * ms + r) * XROW + kc * 128 + q * 32;
            const float4 lo = *(const float4*)p;
            const float4 hi = *(const float4*)(p + 16);
            bf16x8 a;
            a[0] = (short)f2bf(lo.x); a[1] = (short)f2bf(lo.y);
            a[2] = (short)f2bf(lo.z); a[3] = (short)f2bf(lo.w);
            a[4] = (short)f2bf(hi.x); a[5] = (short)f2bf(hi.y);
            a[6] = (short)f2bf(hi.z); a[7] = (short)f2bf(hi.w);
            a1[ms][kc] = a;
        }
    __syncthreads();   // xl reads done everywhere; h may overlay from here on

    float hv[4][2][2][4];   // fp32 h kept for the exact gate (64 VGPRs)

    // ================= GEMM1 (chunks 0..3) =================
#pragma unroll
    for (int c = 0; c < 4; ++c) {
        const int boff = (c & 1) ? WB1_OFF : WB0_OFF;
        if (c < 3) stageW(W1b, c + 1, (c & 1) ? WB0_OFF : WB1_OFF);
        else       stageW(W2b, 0, WB0_OFF);          // pipeline rolls into GEMM2

        bf16x8 Bf[2][8];
#pragma unroll
        for (int ns = 0; ns < 2; ++ns)
#pragma unroll
            for (int kc = 0; kc < 8; ++kc) {
                const int lr = 16 * ns + r;
                Bf[ns][kc] = *(const bf16x8*)(smem + boff + (ch * 16 + (lr >> 1)) * WPAIR
                                              + (lr & 1) * 512 + kc * 64 + q * 16);
            }
        f32x4 acc[2][2];
#pragma unroll
        for (int ms = 0; ms < 2; ++ms)
#pragma unroll
            for (int ns = 0; ns < 2; ++ns) acc[ms][ns] = (f32x4){0.f, 0.f, 0.f, 0.f};
#pragma unroll
        for (int kc = 0; kc < 8; ++kc)
#pragma unroll
            for (int ms = 0; ms < 2; ++ms)
#pragma unroll
                for (int ns = 0; ns < 2; ++ns)
                    acc[ms][ns] = __builtin_amdgcn_mfma_f32_16x16x32_bf16(a1[ms][kc], Bf[ns][kc], acc[ms][ns], 0, 0, 0);

#pragma unroll
        for (int ms = 0; ms < 2; ++ms)
#pragma unroll
            for (int ns = 0; ns < 2; ++ns)
#pragma unroll
                for (int e = 0; e < 4; ++e) {
                    float h = acc[ms][ns][e] + bias1[c][ns];
                    h = fmaxf(h, 0.f);
                    hv[c][ms][ns][e] = h;
                    const int row = 32 * rh + 16 * ms + q * 4 + e;
                    const int col = 128 * ch + 32 * c + 16 * ns + r;
                    *(unsigned short*)(smem + XL_OFF + row * HROW + col * 2) = (unsigned short)f2bf(h);
                }
        __syncthreads();   // chunk c+1 resident; (after c=3) h complete
    }

    // ---- A2 fragments from h (bf16, direct b128)
    bf16x8 a2[2][8];
#pragma unroll
    for (int ms = 0; ms < 2; ++ms)
#pragma unroll
        for (int kc = 0; kc < 8; ++kc)
            a2[ms][kc] = *(const bf16x8*)(smem + XL_OFF + (32 * rh + 16 * ms + r) * HROW + kc * 64 + q * 16);

    // ================= GEMM2 (chunks 4..7) + gate + reduction =================
#pragma unroll
    for (int c = 0; c < 4; ++c) {
        const int boff = (c & 1) ? WB1_OFF : WB0_OFF;
        if (c < 3) stageW(W2b, c + 1, (c & 1) ? WB0_OFF : WB1_OFF);

        bf16x8 Bf[2][8];
#pragma unroll
        for (int ns = 0; ns < 2; ++ns)
#pragma unroll
            for (int kc = 0; kc < 8; ++kc) {
                const int lr = 16 * ns + r;
                Bf[ns][kc] = *(const bf16x8*)(smem + boff + (ch * 16 + (lr >> 1)) * WPAIR
                                              + (lr & 1) * 512 + kc * 64 + q * 16);
            }
        f32x4 acc[2][2];
#pragma unroll
        for (int ms = 0; ms < 2; ++ms)
#pragma unroll
            for (int ns = 0; ns < 2; ++ns) acc[ms][ns] = (f32x4){0.f, 0.f, 0.f, 0.f};
#pragma unroll
        for (int kc = 0; kc < 8; ++kc)
#pragma unroll
            for (int ms = 0; ms < 2; ++ms)
#pragma unroll
                for (int ns = 0; ns < 2; ++ns)
                    acc[ms][ns] = __builtin_amdgcn_mfma_f32_16x16x32_bf16(a2[ms][kc], Bf[ns][kc], acc[ms][ns], 0, 0, 0);

#pragma unroll
        for (int ns = 0; ns < 2; ++ns) {
            const int col = 128 * ch + 32 * c + 16 * ns + r;
            float g[2][4];
#pragma unroll
            for (int ms = 0; ms < 2; ++ms)
#pragma unroll
                for (int e = 0; e < 4; ++e) {
                    const float t   = acc[ms][ns][e] + bias2[c][ns];
                    const float att = 1.f / (1.f + __expf(-t));
                    g[ms][e] = hv[c][ms][ns][e] * att;   // g >= 0
                }
            if (wuni) {
                float s = 0.f, m = 0.f;
#pragma unroll
                for (int ms = 0; ms < 2; ++ms)
#pragma unroll
                    for (int e = 0; e < 4; ++e) { s += g[ms][e]; m = fmaxf(m, g[ms][e]); }
                s += __shfl_xor(s, 16, 64);
                s += __shfl_xor(s, 32, 64);
                m = fmaxf(m, __shfl_xor(m, 16, 64));
                m = fmaxf(m, __shfl_xor(m, 32, 64));
                if (q == 0) {
                    atomicAdd(&out[(size_t)wsegc * 512 + 256 + col], s);
                    atomicMax((unsigned int*)&out[(size_t)wsegc * 512 + col], __float_as_uint(m));
                }
            } else {
#pragma unroll
                for (int ms = 0; ms < 2; ++ms) {
                    if (muni[ms]) {
                        float s = g[ms][0] + g[ms][1] + g[ms][2] + g[ms][3];
                        float m = fmaxf(fmaxf(g[ms][0], g[ms][1]), fmaxf(g[ms][2], g[ms][3]));
                        s += __shfl_xor(s, 16, 64);
                        s += __shfl_xor(s, 32, 64);
                        m = fmaxf(m, __shfl_xor(m, 16, 64));
                        m = fmaxf(m, __shfl_xor(m, 32, 64));
                        if (q == 0) {
                            atomicAdd(&out[(size_t)msegc[ms] * 512 + 256 + col], s);
                            atomicMax((unsigned int*)&out[(size_t)msegc[ms] * 512 + col], __float_as_uint(m));
                        }
                    } else {
#pragma unroll
                        for (int e = 0; e < 4; ++e) {
                            atomicAdd(&out[(size_t)esegc[ms][e] * 512 + 256 + col], g[ms][e]);
                            atomicMax((unsigned int*)&out[(size_t)esegc[ms][e] * 512 + col], __float_as_uint(g[ms][e]));
                        }
                    }
                }
            }
        }
        if (c < 3) __syncthreads();
    }

    if (tid < 64) atomicAdd(&counts[clamp_seg(batch[r0 + tid])], 1);
}

__global__ void finalize_kernel(float* __restrict__ out, const int* __restrict__ counts) {
    const int b = blockIdx.x;
    const int c = threadIdx.x;
    const int cnt = counts[b];
    float s = out[(size_t)b * 512 + 256 + c];
    out[(size_t)b * 512 + 256 + c] = cnt > 0 ? s / (float)cnt : 0.0f;
}

extern "C" void kernel_launch(void* const* d_in, const int* in_sizes, int n_in,
                              void* d_out, int out_size, void* d_ws, size_t ws_size,
                              hipStream_t stream) {
    const float* x     = (const float*)d_in[0];
    const int*   batch = (const int*)d_in[1];
    const float* W1    = (const float*)d_in[2];
    const float* b1    = (const float*)d_in[3];
    const float* W2    = (const float*)d_in[4];
    const float* b2    = (const float*)d_in[5];
    float* out = (float*)d_out;

    unsigned short* W1b    = (unsigned short*)d_ws;
    unsigned short* W2b    = W1b + 65536;
    int*            counts = (int*)(W2b + 65536);

    const int Nrows  = in_sizes[0] / H;   // 200000
    const int blocks = Nrows / 64;        // 3125 (exact)

    hipMemsetAsync(d_out, 0, (size_t)out_size * sizeof(float), stream);
    hipMemsetAsync(counts, 0, 512 * sizeof(int), stream);
    conv_w_kernel<<<256, 256, 0, stream>>>(W1, W2, W1b, W2b);
    fused_main<<<blocks, 256, 0, stream>>>(x, batch, W1b, b1, W2b, b2, out, counts);
    finalize_kernel<<<512, 256, 0, stream>>>(out, counts);
}